// Round 6
// baseline (527.041 us; speedup 1.0000x reference)
//
#include <hip/hip_runtime.h>
#include <cstdint>
#include <cmath>

// ---------------------------------------------------------------------------
// Fused attention block for MI355X (gfx950).
// B=2, N=2048, D=2048, H=16, DH=128.  fp16 MFMA compute, fp32 accum.
// R5 change: both GEMMs restructured to the single-barrier double-buffered
// K-loop proven in R4's attn (barrier -> prefetch t+1 -> compute t), so the
// compiler's vmcnt(0)-before-barrier drain lands a full compute phase after
// issue instead of immediately (R4 profile: gemm_qkv MfmaUtil 21%, VALUBusy
// 9.5%, HBM 9% -> pure latency stall in the 2-barrier shape).
// MFMA fragment layouts (HW-verified):
//   C/D: col = lane&15, row = (lane>>4)*4 + reg
//   A:   m  = lane&15, k = (lane>>4)*8 + j
//   B:   n  = lane&15, k = (lane>>4)*8 + j
// ---------------------------------------------------------------------------

typedef _Float16 h8   __attribute__((ext_vector_type(8)));
typedef _Float16 h4   __attribute__((ext_vector_type(4)));
typedef float    f32x4 __attribute__((ext_vector_type(4)));

#define NB   2
#define NN   2048
#define ND   2048
#define NH   16
#define NDH  128
#define BNR  4096
#define KDIM 2048
#define ATT_SCALE 0.08838834764831845f   // 128^-0.5
#define LOG2E     1.44269504088896f
#define PSHIFT    -4.0f                   // fixed log2-domain shift (cancels)

#define GLOAD_LDS16(gptr, lptr)                                               \
  __builtin_amdgcn_global_load_lds(                                           \
      (__attribute__((address_space(1))) void*)(gptr),                        \
      (__attribute__((address_space(3))) void*)(lptr), 16, 0, 0)

// ---------------- 1. convert x to fp16 ----------------
__global__ __launch_bounds__(256) void cvt_x(const float* __restrict__ x,
                                             _Float16* __restrict__ xh) {
  int i = blockIdx.x * 256 + threadIdx.x;
  float4 v = ((const float4*)x)[i];
  h4 o;
  o[0] = (_Float16)v.x; o[1] = (_Float16)v.y;
  o[2] = (_Float16)v.z; o[3] = (_Float16)v.w;
  ((h4*)xh)[i] = o;
}

// ---------------- 2. transpose weights (K x N fp32) -> (N x K fp16) --------
__global__ __launch_bounds__(256) void transpose4(
    const float* __restrict__ W0, const float* __restrict__ W1,
    const float* __restrict__ W2, const float* __restrict__ W3,
    _Float16* __restrict__ T0, _Float16* __restrict__ T1,
    _Float16* __restrict__ T2, _Float16* __restrict__ T3) {
  const float* W; _Float16* T;
  switch (blockIdx.z) {
    case 0: W = W0; T = T0; break;
    case 1: W = W1; T = T1; break;
    case 2: W = W2; T = T2; break;
    default: W = W3; T = T3; break;
  }
  __shared__ float tile[32][33];
  int tx = threadIdx.x, ty = threadIdx.y;          // block (32,8)
  int n0 = blockIdx.x * 32, k0 = blockIdx.y * 32;
#pragma unroll
  for (int j = 0; j < 4; ++j)
    tile[ty + j * 8][tx] = W[(size_t)(k0 + ty + j * 8) * ND + n0 + tx];
  __syncthreads();
#pragma unroll
  for (int j = 0; j < 4; ++j)
    T[(size_t)(n0 + ty + j * 8) * KDIM + k0 + tx] =
        (_Float16)tile[tx][ty + j * 8];
}

// ---------------- 2b. transpose Wg (2048x16 fp32) -> Wgt (16x2048 fp16) ----
__global__ __launch_bounds__(256) void wg_transpose(
    const float* __restrict__ Wg, _Float16* __restrict__ Wgt) {
  int i = blockIdx.x * 256 + threadIdx.x;          // 32768 elements
  int k = i >> 4, h = i & 15;
  Wgt[(size_t)h * KDIM + k] = (_Float16)Wg[i];
}

// ---------------- 2c. cos/sin table: cs[n*128+d] = (cos f, sin f) ----------
__global__ __launch_bounds__(256) void build_cs(const float* __restrict__ f,
                                                float2* __restrict__ cs) {
  int i = blockIdx.x * 256 + threadIdx.x;          // NN*NDH = 262144
  float v = f[i];
  cs[i] = make_float2(cosf(v), sinf(v));
}

// ---------------- 3. fused QKV GEMM (1-barrier double-buffered) ------------
// C(4096x6144) = xh(4096x2048) * Bqkv(6144x2048)^T; block col picks proj.
__global__ __launch_bounds__(256) void gemm_qkv(
    const _Float16* __restrict__ A, const _Float16* __restrict__ Bqkv,
    _Float16* __restrict__ qh, _Float16* __restrict__ kh,
    _Float16* __restrict__ vt) {
  __shared__ __align__(16) _Float16 As[2][8 * 512];   // 16 KB
  __shared__ __align__(16) _Float16 Bs[2][8 * 512];   // 16 KB
  int bx = blockIdx.x, by = blockIdx.y;            // bx 0..47
  int proj = bx >> 4;                              // 0=Q 1=K 2=V
  int tid = threadIdx.x;
  int wave = tid >> 6, lane = tid & 63, li = lane & 15, quad = lane >> 4;
  int wm = (wave >> 1) * 64, wn = (wave & 1) * 64;
  int row0 = by * 128;
  int gcol0 = bx * 128;                            // row into Bqkv
  int col0 = (bx & 15) * 128;                      // col within proj
  f32x4 acc[4][4] = {};

  auto stage = [&](int k0, int p) {
#pragma unroll
    for (int t = 0; t < 2; ++t) {
      int blk = wave * 2 + t;
      GLOAD_LDS16(&A[(size_t)(row0 + blk * 16 + li) * KDIM + k0 + quad * 8],
                  &As[p][blk * 512]);
      GLOAD_LDS16(&Bqkv[(size_t)(gcol0 + blk * 16 + li) * KDIM + k0 + quad * 8],
                  &Bs[p][blk * 512]);
    }
  };

  stage(0, 0);
  for (int it = 0; it < KDIM / 32; ++it) {
    int p = it & 1;
    __syncthreads();                       // publishes buf p
    if (it + 1 < KDIM / 32) stage((it + 1) * 32, 1 - p);
    h8 af[4], bf[4];
#pragma unroll
    for (int mi = 0; mi < 4; ++mi)
      af[mi] = *(const h8*)&As[p][((wave >> 1) * 4 + mi) * 512 + lane * 8];
#pragma unroll
    for (int ni = 0; ni < 4; ++ni)
      bf[ni] = *(const h8*)&Bs[p][((wave & 1) * 4 + ni) * 512 + lane * 8];
#pragma unroll
    for (int mi = 0; mi < 4; ++mi)
#pragma unroll
      for (int ni = 0; ni < 4; ++ni)
        acc[mi][ni] = __builtin_amdgcn_mfma_f32_16x16x32_f16(
            af[mi], bf[ni], acc[mi][ni], 0, 0, 0);
  }

#pragma unroll
  for (int mi = 0; mi < 4; ++mi) {
    int gmb = row0 + wm + mi * 16 + quad * 4;
#pragma unroll
    for (int ni = 0; ni < 4; ++ni) {
      int gn = col0 + wn + ni * 16 + li;
      int h = gn >> 7, d = gn & 127;
      if (proj == 2) {                             // V: (B,H,DH,N)
        int b = gmb >> 11, n0 = gmb & 2047;
        h4 tmp;
#pragma unroll
        for (int r = 0; r < 4; ++r) tmp[r] = (_Float16)acc[mi][ni][r];
        *(h4*)&vt[((size_t)(b * NH + h) * NDH + d) * NN + n0] = tmp;
      } else {                                     // Q/K: (B,H,N,DH)
        _Float16* o = proj ? kh : qh;
#pragma unroll
        for (int r = 0; r < 4; ++r) {
          int gm = gmb + r, b = gm >> 11, n = gm & 2047;
          o[((size_t)(b * NH + h) * NN + n) * NDH + d] =
              (_Float16)acc[mi][ni][r];
        }
      }
    }
  }
}

// ---------------- 3b. out-proj GEMM (1-barrier double-buffered) ------------
__global__ __launch_bounds__(256) void gemm_out(
    const _Float16* __restrict__ A, const _Float16* __restrict__ Bt,
    float* __restrict__ dst) {
  __shared__ __align__(16) _Float16 As[2][8 * 512];
  __shared__ __align__(16) _Float16 Bs[2][8 * 512];
  int bx = blockIdx.x, by = blockIdx.y;
  int tid = threadIdx.x;
  int wave = tid >> 6, lane = tid & 63, li = lane & 15, quad = lane >> 4;
  int wm = (wave >> 1) * 64, wn = (wave & 1) * 64;
  int row0 = by * 128, col0 = bx * 128;
  f32x4 acc[4][4] = {};

  auto stage = [&](int k0, int p) {
#pragma unroll
    for (int t = 0; t < 2; ++t) {
      int blk = wave * 2 + t;
      GLOAD_LDS16(&A[(size_t)(row0 + blk * 16 + li) * KDIM + k0 + quad * 8],
                  &As[p][blk * 512]);
      GLOAD_LDS16(&Bt[(size_t)(col0 + blk * 16 + li) * KDIM + k0 + quad * 8],
                  &Bs[p][blk * 512]);
    }
  };

  stage(0, 0);
  for (int it = 0; it < KDIM / 32; ++it) {
    int p = it & 1;
    __syncthreads();
    if (it + 1 < KDIM / 32) stage((it + 1) * 32, 1 - p);
    h8 af[4], bf[4];
#pragma unroll
    for (int mi = 0; mi < 4; ++mi)
      af[mi] = *(const h8*)&As[p][((wave >> 1) * 4 + mi) * 512 + lane * 8];
#pragma unroll
    for (int ni = 0; ni < 4; ++ni)
      bf[ni] = *(const h8*)&Bs[p][((wave & 1) * 4 + ni) * 512 + lane * 8];
#pragma unroll
    for (int mi = 0; mi < 4; ++mi)
#pragma unroll
      for (int ni = 0; ni < 4; ++ni)
        acc[mi][ni] = __builtin_amdgcn_mfma_f32_16x16x32_f16(
            af[mi], bf[ni], acc[mi][ni], 0, 0, 0);
  }

#pragma unroll
  for (int mi = 0; mi < 4; ++mi) {
    int gmb = row0 + wm + mi * 16 + quad * 4;
#pragma unroll
    for (int ni = 0; ni < 4; ++ni) {
      int gn = col0 + wn + ni * 16 + li;
#pragma unroll
      for (int r = 0; r < 4; ++r)
        dst[(size_t)(gmb + r) * ND + gn] = acc[mi][ni][r];
    }
  }
}

// ---------------- 4. RoPE on qh, kh (table-driven) -------------------------
__global__ __launch_bounds__(256) void rope_kernel(
    _Float16* __restrict__ qh, _Float16* __restrict__ kh,
    const float2* __restrict__ cs) {
  int i = blockIdx.x * 256 + threadIdx.x;
  int d = i & 63;
  int rest = i >> 6;
  int n = rest & 2047;
  int bh = rest >> 11;
  size_t base = (size_t)bh * NN * NDH + (size_t)n * NDH;
  float2 cs1 = cs[n * NDH + d];
  float2 cs2 = cs[n * NDH + d + 64];
  float q1 = (float)qh[base + d], q2 = (float)qh[base + d + 64];
  qh[base + d]      = (_Float16)(q1 * cs1.x - q2 * cs1.y);
  qh[base + d + 64] = (_Float16)(q2 * cs2.x + q1 * cs2.y);
  float k1 = (float)kh[base + d], k2 = (float)kh[base + d + 64];
  kh[base + d]      = (_Float16)(k1 * cs1.x - k2 * cs1.y);
  kh[base + d + 64] = (_Float16)(k2 * cs2.x + k1 * cs2.y);
}

// ---------------- 5. gate = sigmoid(xh @ Wgt^T + bg) via MFMA --------------
__global__ __launch_bounds__(256) void gate_mfma(
    const _Float16* __restrict__ xh, const _Float16* __restrict__ Wgt,
    const float* __restrict__ bg, float* __restrict__ gate) {
  __shared__ float red[4][16][16];
  int tid = threadIdx.x, wave = tid >> 6, lane = tid & 63;
  int li = lane & 15, quad = lane >> 4;
  int m0 = blockIdx.x * 16;
  f32x4 acc = {};
#pragma unroll
  for (int it = 0; it < 16; ++it) {
    int k0 = wave * 512 + it * 32;
    h8 af = *(const h8*)&xh[(size_t)(m0 + li) * KDIM + k0 + quad * 8];
    h8 bf = *(const h8*)&Wgt[(size_t)li * KDIM + k0 + quad * 8];
    acc = __builtin_amdgcn_mfma_f32_16x16x32_f16(af, bf, acc, 0, 0, 0);
  }
#pragma unroll
  for (int r = 0; r < 4; ++r) red[wave][quad * 4 + r][li] = acc[r];
  __syncthreads();
  int row = tid >> 4, col = tid & 15;
  float s = red[0][row][col] + red[1][row][col] +
            red[2][row][col] + red[3][row][col];
  float g = 1.f / (1.f + __expf(-(s + bg[col])));
  int token = m0 + row, b = token >> 11, n = token & 2047;
  gate[(size_t)(b * NH + col) * NN + n] = g;
}

// ---------------- 6. flash attention + gating (R4 structure) ---------------
// grid: 32 bh x 16 qblk; 4 waves; wave owns 32 q-rows (2 B-frag sets);
// kv-tile 64, double-buffered K/V, ONE barrier per iteration.
__global__ __launch_bounds__(256, 2) void attn_kernel(
    const _Float16* __restrict__ qh, const _Float16* __restrict__ kh,
    const _Float16* __restrict__ vt, const float* __restrict__ gate,
    _Float16* __restrict__ attn) {
  __shared__ __align__(16) _Float16 KsL[2][16 * 512];   // 32 KB
  __shared__ __align__(16) _Float16 VsL[2][16 * 512];   // 32 KB
  int bh = blockIdx.x >> 4, qblk = blockIdx.x & 15;
  int tid = threadIdx.x, wave = tid >> 6, lane = tid & 63;
  int li = lane & 15, quad = lane >> 4;
  int q0 = qblk * 128 + wave * 32;
  const _Float16* qb = qh + (size_t)bh * NN * NDH;
  const _Float16* kb = kh + (size_t)bh * NN * NDH;
  const _Float16* vb = vt + (size_t)bh * NDH * NN;

  // Q B-frags (two 16-row sets), pre-scaled by ATT_SCALE*log2(e)
  h8 bq[2][4];
  const float qs = ATT_SCALE * LOG2E;
#pragma unroll
  for (int s = 0; s < 2; ++s)
#pragma unroll
    for (int kk = 0; kk < 4; ++kk) {
      h8 t = *(const h8*)&qb[(size_t)(q0 + s * 16 + li) * NDH + kk * 32 + quad * 8];
#pragma unroll
      for (int j = 0; j < 8; ++j) t[j] = (_Float16)((float)t[j] * qs);
      bq[s][kk] = t;
    }

  // V staging roles
  int vd = tid >> 1, vw = tid & 1;
  int vli = vd & 15, vc2base = (vd >> 4) * 2;
  int slotR = ((quad * 16 + li) ^ ((li >> 3) * 2) ^ quad);

  float l_lane[2] = {0.f, 0.f};
  f32x4 o[2][8] = {};
  h8 vr[4];

  auto stageK = [&](int kv0, int p) {
#pragma unroll
    for (int t = 0; t < 4; ++t) {
      int c = wave * 4 + t, n2 = c >> 2, kk2 = c & 3;
      GLOAD_LDS16(&kb[(size_t)(kv0 + n2 * 16 + li) * NDH + kk2 * 32 + quad * 8],
                  &KsL[p][c * 512]);
    }
  };
  auto loadV = [&](int kv0) {
#pragma unroll
    for (int u = 0; u < 4; ++u)
      vr[u] = *(const h8*)&vb[(size_t)vd * NN + kv0 + u * 16 + vw * 8];
  };
  auto writeV = [&](int p) {
#pragma unroll
    for (int u = 0; u < 4; ++u) {
      int c2 = vc2base + (u & 1), bb = u >> 1;
#pragma unroll
      for (int hi = 0; hi < 2; ++hi) {
        int quadV = 2 * vw + hi;
        int L = quadV * 16 + vli;
        int slot = L ^ ((vli >> 3) * 2) ^ quadV;
        h4 piece;
        piece[0] = vr[u][hi * 4 + 0]; piece[1] = vr[u][hi * 4 + 1];
        piece[2] = vr[u][hi * 4 + 2]; piece[3] = vr[u][hi * 4 + 3];
        *(h4*)&VsL[p][c2 * 512 + slot * 8 + bb * 4] = piece;
      }
    }
  };

  // prologue: stage tile 0 into buffer 0
  stageK(0, 0);
  loadV(0);
  writeV(0);

  for (int t = 0; t < NN / 64; ++t) {
    int p = t & 1;
    __syncthreads();                       // publishes tile t (buf p)
    int kvn = (t + 1) * 64;
    if (kvn < NN) {                        // prefetch t+1 into buf 1-p
      stageK(kvn, 1 - p);
      loadV(kvn);
    }

    // S^T = K Q^T (C-init = PSHIFT folds the softmax shift)
    f32x4 st[2][4];
#pragma unroll
    for (int s = 0; s < 2; ++s)
#pragma unroll
      for (int n2 = 0; n2 < 4; ++n2)
        st[s][n2] = (f32x4){PSHIFT, PSHIFT, PSHIFT, PSHIFT};
#pragma unroll
    for (int n2 = 0; n2 < 4; ++n2)
#pragma unroll
      for (int kk = 0; kk < 4; ++kk) {
        h8 kf = *(const h8*)&KsL[p][(n2 * 4 + kk) * 512 + lane * 8];
        st[0][n2] = __builtin_amdgcn_mfma_f32_16x16x32_f16(kf, bq[0][kk], st[0][n2], 0, 0, 0);
        st[1][n2] = __builtin_amdgcn_mfma_f32_16x16x32_f16(kf, bq[1][kk], st[1][n2], 0, 0, 0);
      }

    // p = exp2(st); in-register pack to PV A-frags (pi order)
    h8 pa0[2], pa1[2];
#pragma unroll
    for (int s = 0; s < 2; ++s) {
      float ls = 0.f;
#pragma unroll
      for (int r = 0; r < 4; ++r) {
        float p0 = exp2f(st[s][0][r]);
        float p1 = exp2f(st[s][1][r]);
        float p2 = exp2f(st[s][2][r]);
        float p3 = exp2f(st[s][3][r]);
        ls += (p0 + p1) + (p2 + p3);
        pa0[s][r] = (_Float16)p0; pa0[s][4 + r] = (_Float16)p2;
        pa1[s][r] = (_Float16)p1; pa1[s][4 + r] = (_Float16)p3;
      }
      l_lane[s] += ls;
    }

    // O += P V
#pragma unroll
    for (int ni = 0; ni < 8; ++ni) {
      h8 v0 = *(const h8*)&VsL[p][(ni * 2 + 0) * 512 + slotR * 8];
      h8 v1 = *(const h8*)&VsL[p][(ni * 2 + 1) * 512 + slotR * 8];
      o[0][ni] = __builtin_amdgcn_mfma_f32_16x16x32_f16(pa0[0], v0, o[0][ni], 0, 0, 0);
      o[0][ni] = __builtin_amdgcn_mfma_f32_16x16x32_f16(pa1[0], v1, o[0][ni], 0, 0, 0);
      o[1][ni] = __builtin_amdgcn_mfma_f32_16x16x32_f16(pa0[1], v0, o[1][ni], 0, 0, 0);
      o[1][ni] = __builtin_amdgcn_mfma_f32_16x16x32_f16(pa1[1], v1, o[1][ni], 0, 0, 0);
    }

    if (kvn < NN) writeV(1 - p);           // after compute: load overlapped
  }

  // epilogue: reduce l per row, normalize, gate, store
  int b = bh >> 4, h = bh & 15;
#pragma unroll
  for (int s = 0; s < 2; ++s) {
    float l_all = l_lane[s];
    l_all += __shfl_xor(l_all, 16, 64);
    l_all += __shfl_xor(l_all, 32, 64);    // row-(q0+s*16+li) total
#pragma unroll
    for (int r = 0; r < 4; ++r) {
      float lr = __shfl(l_all, quad * 4 + r, 64);
      int qrow = q0 + s * 16 + quad * 4 + r;
      float g = gate[(size_t)bh * NN + qrow] / lr;
#pragma unroll
      for (int ni = 0; ni < 8; ++ni)
        attn[((size_t)(b * NN + qrow)) * ND + h * NDH + ni * 16 + li] =
            (_Float16)(o[s][ni][r] * g);
    }
  }
}

// ---------------------------------------------------------------------------
extern "C" void kernel_launch(void* const* d_in, const int* in_sizes, int n_in,
                              void* d_out, int out_size, void* d_ws,
                              size_t ws_size, hipStream_t stream) {
  const float* x    = (const float*)d_in[0];
  const float* rpe  = (const float*)d_in[1];
  const float* Wq   = (const float*)d_in[2];
  const float* Wk   = (const float*)d_in[3];
  const float* Wv   = (const float*)d_in[4];
  const float* Wg   = (const float*)d_in[5];
  const float* bg   = (const float*)d_in[6];
  const float* Wo   = (const float*)d_in[7];
  float* out = (float*)d_out;

  char* ws = (char*)d_ws;
  size_t off = 0;
  auto alloc = [&](size_t bytes) {
    void* p = ws + off;
    off += (bytes + 255) & ~(size_t)255;
    return p;
  };
  _Float16* xh   = (_Float16*)alloc((size_t)BNR * KDIM * 2);           // 16 MB
  _Float16* Wqkv = (_Float16*)alloc((size_t)3 * ND * KDIM * 2);        // 24 MB
  _Float16* Wot  = (_Float16*)alloc((size_t)ND * KDIM * 2);            // 8 MB
  _Float16* qh   = (_Float16*)alloc((size_t)NB * NH * NN * NDH * 2);   // 16 MB
  _Float16* kh   = (_Float16*)alloc((size_t)NB * NH * NN * NDH * 2);
  _Float16* vt   = (_Float16*)alloc((size_t)NB * NH * NDH * NN * 2);
  _Float16* attn = (_Float16*)alloc((size_t)BNR * ND * 2);             // 16 MB
  float*    gate = (float*)alloc((size_t)NB * NH * NN * 4);
  _Float16* Wgt  = (_Float16*)alloc((size_t)NH * KDIM * 2);
  float2*   cs   = (float2*)alloc((size_t)NN * NDH * 8);               // 2 MB

  _Float16* Wqt = Wqkv;
  _Float16* Wkt = Wqkv + (size_t)ND * KDIM;
  _Float16* Wvt = Wqkv + (size_t)2 * ND * KDIM;

  cvt_x<<<BNR * KDIM / 1024, 256, 0, stream>>>(x, xh);
  transpose4<<<dim3(64, 64, 4), dim3(32, 8), 0, stream>>>(
      Wq, Wk, Wv, Wo, Wqt, Wkt, Wvt, Wot);
  wg_transpose<<<KDIM * NH / 256, 256, 0, stream>>>(Wg, Wgt);
  build_cs<<<NN * NDH / 256, 256, 0, stream>>>(rpe, cs);
  gemm_qkv<<<dim3(48, 32), 256, 0, stream>>>(xh, Wqkv, qh, kh, vt);
  rope_kernel<<<NB * NH * NN * 64 / 256, 256, 0, stream>>>(qh, kh, cs);
  gate_mfma<<<BNR / 16, 256, 0, stream>>>(xh, Wgt, bg, gate);
  attn_kernel<<<NB * NH * (NN / 128), 256, 0, stream>>>(qh, kh, vt, gate, attn);
  gemm_out<<<dim3(16, 32), 256, 0, stream>>>(attn, Wot, out);
}